// Round 9
// baseline (90.001 us; speedup 1.0000x reference)
//
#include <hip/hip_runtime.h>
#include <math.h>

typedef __attribute__((ext_vector_type(8))) short bf16x8;
typedef __attribute__((ext_vector_type(4))) short bf16x4;
typedef __attribute__((ext_vector_type(4))) float f32x4;

__device__ inline ushort f2bf(float f) {
    union { float f; uint u; } v; v.f = f;
    uint u = v.u;
    return (ushort)((u + 0x7fff + ((u >> 16) & 1)) >> 16);   // RNE
}
__device__ inline float bf2f(ushort u) {
    union { uint u; float f; } v; v.u = ((uint)u) << 16; return v.f;
}

// ---------------------------------------------------------------------------
// MFMA bf16 GEMM, converts inputs on the fly.  (unchanged; passed R3-R8)
// ---------------------------------------------------------------------------
template<int BM, int BN, int WGM, int WGN, int MODE>
__global__ __launch_bounds__(WGM * WGN * 64) void gemm_fused(
    const void* __restrict__ Ap, const float* __restrict__ Bw, int ldb,
    const float* __restrict__ bias,
    void* __restrict__ C0, void* __restrict__ C1, void* __restrict__ C2,
    int K, int N)
{
    constexpr int BK = 32;
    constexpr int NT = WGM * WGN * 64;
    constexpr int WM = BM / (WGM * 16);
    constexpr int WN = BN / (WGN * 16);

    __shared__ ushort As[BM * BK];
    __shared__ ushort Bs[BN * BK];

    const int tid = threadIdx.x;
    const int lane = tid & 63, wid = tid >> 6;
    const int wm = wid / WGN, wn = wid % WGN;
    const int row0 = blockIdx.y * BM, col0 = blockIdx.x * BN;
    const int frow = lane & 15, fg = lane >> 4;

    f32x4 acc[WM][WN] = {};

    for (int k0 = 0; k0 < K; k0 += BK) {
        if constexpr (MODE == 0) {
            #pragma unroll
            for (int ci = tid; ci < BM * 8; ci += NT) {
                int r = ci >> 3, kq = ci & 7, g = kq >> 1;
                float4 v = *(const float4*)((const float*)Ap + (size_t)(row0 + r) * K + k0 + kq * 4);
                bf16x4 o;
                o[0] = (short)f2bf(v.x); o[1] = (short)f2bf(v.y);
                o[2] = (short)f2bf(v.z); o[3] = (short)f2bf(v.w);
                *(bf16x4*)&As[r * 32 + ((g ^ ((r >> 1) & 3)) << 3) + (kq & 1) * 4] = o;
            }
        } else {
            #pragma unroll
            for (int ci = tid; ci < BM * 4; ci += NT) {
                int r = ci >> 2, g = ci & 3;
                bf16x8 v = *(const bf16x8*)((const ushort*)Ap + (size_t)(row0 + r) * K + k0 + g * 8);
                *(bf16x8*)&As[r * 32 + ((g ^ ((r >> 1) & 3)) << 3)] = v;
            }
        }
        #pragma unroll
        for (int ci = tid; ci < BN * 8; ci += NT) {
            int kk = ci & 31, n4 = ci >> 5;
            float4 v = *(const float4*)&Bw[(size_t)(k0 + kk) * ldb + col0 + n4 * 4];
            float vv[4] = {v.x, v.y, v.z, v.w};
            #pragma unroll
            for (int e = 0; e < 4; ++e) {
                int n = n4 * 4 + e;
                Bs[n * 32 + (((kk >> 3) ^ ((n >> 1) & 3)) << 3) + (kk & 7)] = f2bf(vv[e]);
            }
        }
        __syncthreads();

        bf16x8 af[WM], bfr[WN];
        #pragma unroll
        for (int m = 0; m < WM; ++m) {
            int r = (wm * WM + m) * 16 + frow;
            af[m] = *(const bf16x8*)&As[r * 32 + ((fg ^ ((r >> 1) & 3)) << 3)];
        }
        #pragma unroll
        for (int n = 0; n < WN; ++n) {
            int r = (wn * WN + n) * 16 + frow;
            bfr[n] = *(const bf16x8*)&Bs[r * 32 + ((fg ^ ((r >> 1) & 3)) << 3)];
        }
        #pragma unroll
        for (int m = 0; m < WM; ++m)
            #pragma unroll
            for (int n = 0; n < WN; ++n)
                acc[m][n] = __builtin_amdgcn_mfma_f32_16x16x32_bf16(
                    af[m], bfr[n], acc[m][n], 0, 0, 0);
        __syncthreads();
    }

    #pragma unroll
    for (int n = 0; n < WN; ++n) {
        int gcol = col0 + (wn * WN + n) * 16 + frow;
        float bv = bias[gcol];
        if constexpr (MODE == 0) {
            int b = gcol >> 8, c = gcol & 255;
            ushort* dst = (b == 0) ? (ushort*)C0 : (b == 1) ? (ushort*)C1 : (ushort*)C2;
            #pragma unroll
            for (int m = 0; m < WM; ++m) {
                int grow0 = row0 + (wm * WM + m) * 16 + fg * 4;
                #pragma unroll
                for (int r = 0; r < 4; ++r)
                    dst[(size_t)(grow0 + r) * 256 + c] = f2bf(acc[m][n][r] + bv);
            }
        } else {
            float* dst = (float*)C0;
            #pragma unroll
            for (int m = 0; m < WM; ++m) {
                int grow0 = row0 + (wm * WM + m) * 16 + fg * 4;
                #pragma unroll
                for (int r = 0; r < 4; ++r)
                    dst[(size_t)(grow0 + r) * N + gcol] = acc[m][n][r] + bv;
            }
        }
    }
}

// ---------------------------------------------------------------------------
// Pass A: scores. Pure streaming, fill-kernel shape.
// Wave-task T = item*32 + j (131072 tasks, 4096 waves x 32 grid-stride iters).
// Lane = h*8 + dq. Per iter: bias 1KB contiguous, k 512B contiguous,
// q 512B contiguous, 4 FMA, 3-level shfl_xor reduce, 1 dword store per 8 lanes.
// All iterations independent -> deep MLP.
// ---------------------------------------------------------------------------
__global__ __launch_bounds__(256) void score_kernel(
    const ushort* __restrict__ qb, const ushort* __restrict__ kb,
    const float* __restrict__ bias, const int* __restrict__ mask,
    float* __restrict__ s_out)
{
    const int lane = threadIdx.x & 63;
    const int wv = (blockIdx.x << 2) | (threadIdx.x >> 6);   // 0..4095
    const int h = lane >> 3;

    #pragma unroll 4
    for (int T = wv; T < 131072; T += 4096) {
        const int item = T >> 5, j = T & 31;
        const int r = ((T >> 10) << 5) | j;                  // k/v/mask row
        float4 b4 = ((const float4*)(bias + (size_t)T * 256))[lane];
        bf16x4 k4 = ((const bf16x4*)(kb + (size_t)r * 256))[lane];
        bf16x4 q4 = ((const bf16x4*)(qb + (size_t)item * 256))[lane];
        float s = bf2f((ushort)q4[0]) * (bf2f((ushort)k4[0]) + b4.x)
                + bf2f((ushort)q4[1]) * (bf2f((ushort)k4[1]) + b4.y)
                + bf2f((ushort)q4[2]) * (bf2f((ushort)k4[2]) + b4.z)
                + bf2f((ushort)q4[3]) * (bf2f((ushort)k4[3]) + b4.w);
        s += __shfl_xor(s, 1);
        s += __shfl_xor(s, 2);
        s += __shfl_xor(s, 4);
        if ((lane & 7) == 0) {
            const bool alive = (mask[r] != 0);
            s_out[(size_t)T * 8 + h] =
                alive ? s * 0.17677669529663687f : -__builtin_inff();
        }
    }
}

// ---------------------------------------------------------------------------
// Pass B: softmax + v-only PV partial. Block per item (tiny traffic).
// Reads s (coalesced), softmax per (h-row) in 32-lane groups, writes
// p (f32, in place over s) and ov = sum_j p*v (bf16).
// ---------------------------------------------------------------------------
__global__ __launch_bounds__(256) void softmax_pv_kernel(
    const ushort* __restrict__ vb, const int* __restrict__ mask,
    float* __restrict__ sp, ushort* __restrict__ ov_out)
{
    __shared__ float xs[256];
    __shared__ float ps[256];

    const int item = blockIdx.x, bt = item >> 5, tid = threadIdx.x;

    xs[tid] = sp[(size_t)item * 256 + tid];      // s in [j][h] order, coalesced
    __syncthreads();

    const int h = tid >> 5, j = tid & 31;
    float s = xs[j * 8 + h];
    __syncthreads();                             // all reads done before rewrite

    const bool alive = (mask[bt * 32 + j] != 0);
    float m = s;
    #pragma unroll
    for (int off = 16; off; off >>= 1) m = fmaxf(m, __shfl_xor(m, off));
    const bool dead = (m == -__builtin_inff());
    float p = alive ? __expf(s - m) : 0.f;
    float l = p;
    #pragma unroll
    for (int off = 16; off; off >>= 1) l += __shfl_xor(l, off);
    float pn = dead ? 0.f : p / l;

    ps[tid] = pn;                                // ps[h*32 + j]
    xs[j * 8 + h] = pn;                          // linear [j][h] for writeback
    __syncthreads();

    sp[(size_t)item * 256 + tid] = xs[tid];      // p writeback, coalesced

    // v-only PV: thread = (h2, d) == tid
    const int hbase = tid & 0xE0;
    float o = 0.f;
    #pragma unroll
    for (int jj = 0; jj < 32; ++jj)
        o += ps[hbase | jj] * bf2f(vb[(size_t)bt * 8192 + jj * 256 + tid]);
    ov_out[(size_t)item * 256 + tid] = f2bf(o);
}

// ---------------------------------------------------------------------------
// Pass C: bias-PV term + combine. Wave = one item; 32 independent 1KB
// contiguous bias reads (L3-resident from pass A) x p-broadcast FMA.
// ---------------------------------------------------------------------------
__global__ __launch_bounds__(256) void pvb_kernel(
    const float* __restrict__ bias, const float* __restrict__ p_in,
    const ushort* __restrict__ ov_in, ushort* __restrict__ ao)
{
    const int lane = threadIdx.x & 63;
    const int item = (blockIdx.x << 2) | (threadIdx.x >> 6);  // 0..4095
    const int h = lane >> 3;
    const float* bbase = bias + (size_t)item * 8192;
    const float* pbase = p_in + (size_t)item * 256;

    float ox = 0.f, oy = 0.f, oz = 0.f, ow = 0.f;
    #pragma unroll 8
    for (int j = 0; j < 32; ++j) {
        float4 b4 = ((const float4*)(bbase + j * 256))[lane];
        float pj = pbase[j * 8 + h];
        ox += pj * b4.x; oy += pj * b4.y; oz += pj * b4.z; ow += pj * b4.w;
    }
    bf16x4 ov4 = ((const bf16x4*)(ov_in + (size_t)item * 256))[lane];
    bf16x4 rr;
    rr[0] = (short)f2bf(ox + bf2f((ushort)ov4[0]));
    rr[1] = (short)f2bf(oy + bf2f((ushort)ov4[1]));
    rr[2] = (short)f2bf(oz + bf2f((ushort)ov4[2]));
    rr[3] = (short)f2bf(ow + bf2f((ushort)ov4[3]));
    ((bf16x4*)(ao + (size_t)item * 256))[lane] = rr;
}

extern "C" void kernel_launch(void* const* d_in, const int* in_sizes, int n_in,
                              void* d_out, int out_size, void* d_ws, size_t ws_size,
                              hipStream_t stream) {
    const float* x      = (const float*)d_in[0];   // (4096,256)
    const float* bias_f = (const float*)d_in[1];   // (4096,32,256)
    const int*   mask   = (const int*)d_in[2];     // (4096,)
    const float* w_qkv  = (const float*)d_in[3];   // (256,768)
    const float* b_qkv  = (const float*)d_in[4];   // (768,)
    const float* w_proj = (const float*)d_in[5];   // (256,256)
    const float* b_proj = (const float*)d_in[6];   // (256,)
    float* out = (float*)d_out;                    // (4096,256)

    // workspace (bytes):
    //   qb  0        kb  2097152   vb  4194304   ao  6291456   (bf16, 2MB each)
    //   sp  8388608  (f32 4MB, s then p in-place)
    //   ov  12582912 (bf16 2MB)                       total 14.7 MB
    char* ws = (char*)d_ws;
    ushort* qb = (ushort*)ws;
    ushort* kb = (ushort*)(ws + 2097152);
    ushort* vb = (ushort*)(ws + 4194304);
    ushort* ao = (ushort*)(ws + 6291456);
    float*  sp = (float*)(ws + 8388608);
    ushort* ov = (ushort*)(ws + 12582912);

    // qkv = x @ w_qkv + b_qkv  ->  bf16 q/k/v   (M=4096, N=768, K=256)
    gemm_fused<64, 64, 2, 2, 0><<<dim3(12, 64), 256, 0, stream>>>(
        x, w_qkv, 768, b_qkv, qb, kb, vb, 256, 768);

    score_kernel<<<1024, 256, 0, stream>>>(qb, kb, bias_f, mask, sp);
    softmax_pv_kernel<<<4096, 256, 0, stream>>>(vb, mask, sp, ov);
    pvb_kernel<<<1024, 256, 0, stream>>>(bias_f, sp, ov, ao);

    // out = attn_out @ w_proj + b_proj   (M=4096, N=256, K=256)
    gemm_fused<32, 64, 1, 4, 1><<<dim3(4, 128), 256, 0, stream>>>(
        ao, w_proj, 256, b_proj, out, nullptr, nullptr, 256, 256);
}

// Round 10
// 69.714 us; speedup vs baseline: 1.2910x; 1.2910x over previous
//
#include <hip/hip_runtime.h>
#include <math.h>

typedef __attribute__((ext_vector_type(8))) short bf16x8;
typedef __attribute__((ext_vector_type(4))) short bf16x4;
typedef __attribute__((ext_vector_type(4))) float f32x4;

__device__ inline ushort f2bf(float f) {
    union { float f; uint u; } v; v.f = f;
    uint u = v.u;
    return (ushort)((u + 0x7fff + ((u >> 16) & 1)) >> 16);   // RNE
}
__device__ inline float bf2f(ushort u) {
    union { uint u; float f; } v; v.u = ((uint)u) << 16; return v.f;
}

// ---------------------------------------------------------------------------
// MFMA bf16 GEMM, converts inputs on the fly.  (unchanged; passed R3-R9)
// ---------------------------------------------------------------------------
template<int BM, int BN, int WGM, int WGN, int MODE>
__global__ __launch_bounds__(WGM * WGN * 64) void gemm_fused(
    const void* __restrict__ Ap, const float* __restrict__ Bw, int ldb,
    const float* __restrict__ bias,
    void* __restrict__ C0, void* __restrict__ C1, void* __restrict__ C2,
    int K, int N)
{
    constexpr int BK = 32;
    constexpr int NT = WGM * WGN * 64;
    constexpr int WM = BM / (WGM * 16);
    constexpr int WN = BN / (WGN * 16);

    __shared__ ushort As[BM * BK];
    __shared__ ushort Bs[BN * BK];

    const int tid = threadIdx.x;
    const int lane = tid & 63, wid = tid >> 6;
    const int wm = wid / WGN, wn = wid % WGN;
    const int row0 = blockIdx.y * BM, col0 = blockIdx.x * BN;
    const int frow = lane & 15, fg = lane >> 4;

    f32x4 acc[WM][WN] = {};

    for (int k0 = 0; k0 < K; k0 += BK) {
        if constexpr (MODE == 0) {
            #pragma unroll
            for (int ci = tid; ci < BM * 8; ci += NT) {
                int r = ci >> 3, kq = ci & 7, g = kq >> 1;
                float4 v = *(const float4*)((const float*)Ap + (size_t)(row0 + r) * K + k0 + kq * 4);
                bf16x4 o;
                o[0] = (short)f2bf(v.x); o[1] = (short)f2bf(v.y);
                o[2] = (short)f2bf(v.z); o[3] = (short)f2bf(v.w);
                *(bf16x4*)&As[r * 32 + ((g ^ ((r >> 1) & 3)) << 3) + (kq & 1) * 4] = o;
            }
        } else {
            #pragma unroll
            for (int ci = tid; ci < BM * 4; ci += NT) {
                int r = ci >> 2, g = ci & 3;
                bf16x8 v = *(const bf16x8*)((const ushort*)Ap + (size_t)(row0 + r) * K + k0 + g * 8);
                *(bf16x8*)&As[r * 32 + ((g ^ ((r >> 1) & 3)) << 3)] = v;
            }
        }
        #pragma unroll
        for (int ci = tid; ci < BN * 8; ci += NT) {
            int kk = ci & 31, n4 = ci >> 5;
            float4 v = *(const float4*)&Bw[(size_t)(k0 + kk) * ldb + col0 + n4 * 4];
            float vv[4] = {v.x, v.y, v.z, v.w};
            #pragma unroll
            for (int e = 0; e < 4; ++e) {
                int n = n4 * 4 + e;
                Bs[n * 32 + (((kk >> 3) ^ ((n >> 1) & 3)) << 3) + (kk & 7)] = f2bf(vv[e]);
            }
        }
        __syncthreads();

        bf16x8 af[WM], bfr[WN];
        #pragma unroll
        for (int m = 0; m < WM; ++m) {
            int r = (wm * WM + m) * 16 + frow;
            af[m] = *(const bf16x8*)&As[r * 32 + ((fg ^ ((r >> 1) & 3)) << 3)];
        }
        #pragma unroll
        for (int n = 0; n < WN; ++n) {
            int r = (wn * WN + n) * 16 + frow;
            bfr[n] = *(const bf16x8*)&Bs[r * 32 + ((fg ^ ((r >> 1) & 3)) << 3)];
        }
        #pragma unroll
        for (int m = 0; m < WM; ++m)
            #pragma unroll
            for (int n = 0; n < WN; ++n)
                acc[m][n] = __builtin_amdgcn_mfma_f32_16x16x32_bf16(
                    af[m], bfr[n], acc[m][n], 0, 0, 0);
        __syncthreads();
    }

    #pragma unroll
    for (int n = 0; n < WN; ++n) {
        int gcol = col0 + (wn * WN + n) * 16 + frow;
        float bv = bias[gcol];
        if constexpr (MODE == 0) {
            int b = gcol >> 8, c = gcol & 255;
            ushort* dst = (b == 0) ? (ushort*)C0 : (b == 1) ? (ushort*)C1 : (ushort*)C2;
            #pragma unroll
            for (int m = 0; m < WM; ++m) {
                int grow0 = row0 + (wm * WM + m) * 16 + fg * 4;
                #pragma unroll
                for (int r = 0; r < 4; ++r)
                    dst[(size_t)(grow0 + r) * 256 + c] = f2bf(acc[m][n][r] + bv);
            }
        } else {
            float* dst = (float*)C0;
            #pragma unroll
            for (int m = 0; m < WM; ++m) {
                int grow0 = row0 + (wm * WM + m) * 16 + fg * 4;
                #pragma unroll
                for (int r = 0; r < 4; ++r)
                    dst[(size_t)(grow0 + r) * N + gcol] = acc[m][n][r] + bv;
            }
        }
    }
}

// ---------------------------------------------------------------------------
// Fused relational attention, drain-proof pipelined schedule.
// Grid 1024 (exactly 4 blocks/CU), block = 4 items (same bt).
// One-time: k -> regs, v -> regs, q (all 4 items) -> LDS.
// Bias: 2 x 16KB bf16 double-buffered slabs. Round i:
//   __syncthreads();                 // drains pf_{i+1} (issued a full round
//                                    // earlier -> latency already covered)
//   write slab[(i+1)&1] <- pf regs;  // data ready, no stall
//   issue pf_{i+2};                  // stays in flight through compute
//   compute item i (regs + LDS only, ZERO global loads -> no early drain)
//   store out_i
// Slab layout (proven R5): 16B chunk cc of row j stored at slot cc^(j&7).
// ---------------------------------------------------------------------------
__global__ __launch_bounds__(256, 4) void relattn_kernel(
    const ushort* __restrict__ qb, const ushort* __restrict__ kb,
    const ushort* __restrict__ vb, const float* __restrict__ bias,
    const int* __restrict__ mask, ushort* __restrict__ attn_out)
{
    __shared__ ushort slab[2][32 * 256];   // 2 x 16KB swizzled bias
    __shared__ ushort q_lds[4 * 256];      // 2KB: q rows of the 4 items

    const int b = blockIdx.x;              // 0..1023
    const int item0 = b << 2;
    const int bt = b >> 3;                 // constant across the 4 items
    const int tid = threadIdx.x;
    const int L = tid & 63;
    const int w = tid >> 6;
    const int hw = L >> 5;
    const int h = 2 * w + hw;
    const int jd = L & 31;                 // j in scores, d in PV

    // ---- one-time loads (issued before any pf -> their waits never drain pf) ----
    const bool alive = (mask[bt * 32 + jd] != 0);

    bf16x8 k8[4];
    const ushort* krow = kb + (size_t)(bt * 32 + jd) * 256 + h * 32;
    #pragma unroll
    for (int t = 0; t < 4; ++t) k8[t] = *(const bf16x8*)(krow + t * 8);

    ushort vreg[32];
    const ushort* vbase = vb + (size_t)bt * 8192 + tid;
    #pragma unroll
    for (int jj = 0; jj < 32; ++jj) vreg[jj] = vbase[(size_t)jj * 256];

    bf16x8 qtmp;
    if (tid < 128) qtmp = *(const bf16x8*)(qb + (size_t)item0 * 256 + tid * 8);

    const float* bbase = bias + (size_t)item0 * 8192;

    // pf mapping: g=0..7, idx4 = g*256+tid -> float4; row j = idx4>>6,
    // bf16 16B-chunk cc = (idx4&63)>>1, half = idx4&1.
    float4 pf[8];
    #pragma unroll
    for (int g = 0; g < 8; ++g)
        pf[g] = ((const float4*)bbase)[g * 256 + tid];

    if (tid < 128) *(bf16x8*)&q_lds[tid * 8] = qtmp;

    auto write_slab = [&](ushort* sl) {
        #pragma unroll
        for (int g = 0; g < 8; ++g) {
            int idx4 = g * 256 + tid;
            int j = idx4 >> 6, cc = (idx4 & 63) >> 1, half = idx4 & 1;
            bf16x4 o;
            o[0] = (short)f2bf(pf[g].x); o[1] = (short)f2bf(pf[g].y);
            o[2] = (short)f2bf(pf[g].z); o[3] = (short)f2bf(pf[g].w);
            *(bf16x4*)&sl[j * 256 + ((cc ^ (j & 7)) << 3) + half * 4] = o;
        }
    };

    write_slab(slab[0]);                   // waits pf_0 (prologue only)
    #pragma unroll
    for (int g = 0; g < 8; ++g)            // issue pf_1
        pf[g] = ((const float4*)(bbase + 8192))[g * 256 + tid];

    #pragma unroll
    for (int it = 0; it < 4; ++it) {
        __syncthreads();                   // drains pf_{it+1} (covered by prior compute)

        if (it < 3) write_slab(slab[(it + 1) & 1]);
        if (it < 2) {
            const float* nb = bbase + (size_t)(it + 2) * 8192;
            #pragma unroll
            for (int g = 0; g < 8; ++g)    // issue pf_{it+2}
                pf[g] = ((const float4*)nb)[g * 256 + tid];
        }

        const ushort* cur = slab[it & 1];

        // ---- scores: lane (h, jd); q from LDS broadcast, k from regs ----
        float s = 0.f;
        #pragma unroll
        for (int t = 0; t < 4; ++t) {
            bf16x8 q8 = *(const bf16x8*)&q_lds[it * 256 + h * 32 + t * 8];
            int cc = h * 4 + t;
            bf16x8 b8 = *(const bf16x8*)&cur[jd * 256 + ((cc ^ (jd & 7)) << 3)];
            #pragma unroll
            for (int e = 0; e < 8; ++e)
                s += bf2f((ushort)q8[e]) * (bf2f((ushort)k8[t][e]) + bf2f((ushort)b8[e]));
        }
        s *= 0.17677669529663687f;         // 1/sqrt(32)
        s = alive ? s : -__builtin_inff();

        float m = s;
        #pragma unroll
        for (int off = 16; off; off >>= 1) m = fmaxf(m, __shfl_xor(m, off));
        const bool dead = (m == -__builtin_inff());
        float p = alive ? __expf(s - m) : 0.f;
        float l = p;
        #pragma unroll
        for (int off = 16; off; off >>= 1) l += __shfl_xor(l, off);
        float pn = dead ? 0.f : p / l;

        // ---- PV: lane (h, d=jd), col == tid; v from regs, bias from LDS ----
        const int half32 = L & 32;
        const int ccv = tid >> 3, dlo = tid & 7;
        float o0 = 0.f, o1 = 0.f, o2 = 0.f, o3 = 0.f;
        #pragma unroll
        for (int jq = 0; jq < 8; ++jq) {
            int j0 = jq * 4;
            float pa = __shfl(pn, half32 | (j0 + 0));
            float pb = __shfl(pn, half32 | (j0 + 1));
            float pc = __shfl(pn, half32 | (j0 + 2));
            float pd = __shfl(pn, half32 | (j0 + 3));
            float ba = bf2f(cur[(j0 + 0) * 256 + (((ccv ^ ((j0 + 0) & 7)) << 3) | dlo)]);
            float bb = bf2f(cur[(j0 + 1) * 256 + (((ccv ^ ((j0 + 1) & 7)) << 3) | dlo)]);
            float bc = bf2f(cur[(j0 + 2) * 256 + (((ccv ^ ((j0 + 2) & 7)) << 3) | dlo)]);
            float bd = bf2f(cur[(j0 + 3) * 256 + (((ccv ^ ((j0 + 3) & 7)) << 3) | dlo)]);
            o0 += pa * (bf2f(vreg[j0 + 0]) + ba);
            o1 += pb * (bf2f(vreg[j0 + 1]) + bb);
            o2 += pc * (bf2f(vreg[j0 + 2]) + bc);
            o3 += pd * (bf2f(vreg[j0 + 3]) + bd);
        }
        attn_out[(size_t)(item0 + it) * 256 + tid] = f2bf((o0 + o1) + (o2 + o3));
    }
}

extern "C" void kernel_launch(void* const* d_in, const int* in_sizes, int n_in,
                              void* d_out, int out_size, void* d_ws, size_t ws_size,
                              hipStream_t stream) {
    const float* x      = (const float*)d_in[0];   // (4096,256)
    const float* bias_f = (const float*)d_in[1];   // (4096,32,256)
    const int*   mask   = (const int*)d_in[2];     // (4096,)
    const float* w_qkv  = (const float*)d_in[3];   // (256,768)
    const float* b_qkv  = (const float*)d_in[4];   // (768,)
    const float* w_proj = (const float*)d_in[5];   // (256,256)
    const float* b_proj = (const float*)d_in[6];   // (256,)
    float* out = (float*)d_out;                    // (4096,256)

    // workspace: q,k,v,attn_out each 4096*256 bf16 (2 MB) = 8.4 MB total
    ushort* qb = (ushort*)d_ws;
    ushort* kb = qb + (size_t)4096 * 256;
    ushort* vb = kb + (size_t)4096 * 256;
    ushort* ao = vb + (size_t)4096 * 256;

    // qkv = x @ w_qkv + b_qkv  ->  bf16 q/k/v   (M=4096, N=768, K=256)
    gemm_fused<64, 64, 2, 2, 0><<<dim3(12, 64), 256, 0, stream>>>(
        x, w_qkv, 768, b_qkv, qb, kb, vb, 256, 768);

    relattn_kernel<<<1024, 256, 0, stream>>>(qb, kb, vb, bias_f, mask, ao);

    // out = attn_out @ w_proj + b_proj   (M=4096, N=256, K=256)
    gemm_fused<32, 64, 1, 4, 1><<<dim3(4, 128), 256, 0, stream>>>(
        ao, w_proj, 256, b_proj, out, nullptr, nullptr, 256, 256);
}

// Round 11
// 55.949 us; speedup vs baseline: 1.6086x; 1.2460x over previous
//
#include <hip/hip_runtime.h>
#include <math.h>

typedef __attribute__((ext_vector_type(8))) short bf16x8;
typedef __attribute__((ext_vector_type(4))) short bf16x4;
typedef __attribute__((ext_vector_type(4))) float f32x4;

__device__ inline ushort f2bf(float f) {
    union { float f; uint u; } v; v.f = f;
    uint u = v.u;
    return (ushort)((u + 0x7fff + ((u >> 16) & 1)) >> 16);   // RNE
}
__device__ inline float bf2f(ushort u) {
    union { uint u; float f; } v; v.u = ((uint)u) << 16; return v.f;
}

typedef __attribute__((address_space(1))) const void global_void;
typedef __attribute__((address_space(3))) void lds_void;
__device__ inline void gl_lds16(const void* g, void* l) {
    __builtin_amdgcn_global_load_lds((global_void*)g, (lds_void*)l, 16, 0, 0);
}

// ---------------------------------------------------------------------------
// MFMA bf16 GEMM, converts inputs on the fly.  (unchanged; passed R3-R10)
// ---------------------------------------------------------------------------
template<int BM, int BN, int WGM, int WGN, int MODE>
__global__ __launch_bounds__(WGM * WGN * 64) void gemm_fused(
    const void* __restrict__ Ap, const float* __restrict__ Bw, int ldb,
    const float* __restrict__ bias,
    void* __restrict__ C0, void* __restrict__ C1, void* __restrict__ C2,
    int K, int N)
{
    constexpr int BK = 32;
    constexpr int NT = WGM * WGN * 64;
    constexpr int WM = BM / (WGM * 16);
    constexpr int WN = BN / (WGN * 16);

    __shared__ ushort As[BM * BK];
    __shared__ ushort Bs[BN * BK];

    const int tid = threadIdx.x;
    const int lane = tid & 63, wid = tid >> 6;
    const int wm = wid / WGN, wn = wid % WGN;
    const int row0 = blockIdx.y * BM, col0 = blockIdx.x * BN;
    const int frow = lane & 15, fg = lane >> 4;

    f32x4 acc[WM][WN] = {};

    for (int k0 = 0; k0 < K; k0 += BK) {
        if constexpr (MODE == 0) {
            #pragma unroll
            for (int ci = tid; ci < BM * 8; ci += NT) {
                int r = ci >> 3, kq = ci & 7, g = kq >> 1;
                float4 v = *(const float4*)((const float*)Ap + (size_t)(row0 + r) * K + k0 + kq * 4);
                bf16x4 o;
                o[0] = (short)f2bf(v.x); o[1] = (short)f2bf(v.y);
                o[2] = (short)f2bf(v.z); o[3] = (short)f2bf(v.w);
                *(bf16x4*)&As[r * 32 + ((g ^ ((r >> 1) & 3)) << 3) + (kq & 1) * 4] = o;
            }
        } else {
            #pragma unroll
            for (int ci = tid; ci < BM * 4; ci += NT) {
                int r = ci >> 2, g = ci & 3;
                bf16x8 v = *(const bf16x8*)((const ushort*)Ap + (size_t)(row0 + r) * K + k0 + g * 8);
                *(bf16x8*)&As[r * 32 + ((g ^ ((r >> 1) & 3)) << 3)] = v;
            }
        }
        #pragma unroll
        for (int ci = tid; ci < BN * 8; ci += NT) {
            int kk = ci & 31, n4 = ci >> 5;
            float4 v = *(const float4*)&Bw[(size_t)(k0 + kk) * ldb + col0 + n4 * 4];
            float vv[4] = {v.x, v.y, v.z, v.w};
            #pragma unroll
            for (int e = 0; e < 4; ++e) {
                int n = n4 * 4 + e;
                Bs[n * 32 + (((kk >> 3) ^ ((n >> 1) & 3)) << 3) + (kk & 7)] = f2bf(vv[e]);
            }
        }
        __syncthreads();

        bf16x8 af[WM], bfr[WN];
        #pragma unroll
        for (int m = 0; m < WM; ++m) {
            int r = (wm * WM + m) * 16 + frow;
            af[m] = *(const bf16x8*)&As[r * 32 + ((fg ^ ((r >> 1) & 3)) << 3)];
        }
        #pragma unroll
        for (int n = 0; n < WN; ++n) {
            int r = (wn * WN + n) * 16 + frow;
            bfr[n] = *(const bf16x8*)&Bs[r * 32 + ((fg ^ ((r >> 1) & 3)) << 3)];
        }
        #pragma unroll
        for (int m = 0; m < WM; ++m)
            #pragma unroll
            for (int n = 0; n < WN; ++n)
                acc[m][n] = __builtin_amdgcn_mfma_f32_16x16x32_bf16(
                    af[m], bfr[n], acc[m][n], 0, 0, 0);
        __syncthreads();
    }

    #pragma unroll
    for (int n = 0; n < WN; ++n) {
        int gcol = col0 + (wn * WN + n) * 16 + frow;
        float bv = bias[gcol];
        if constexpr (MODE == 0) {
            int b = gcol >> 8, c = gcol & 255;
            ushort* dst = (b == 0) ? (ushort*)C0 : (b == 1) ? (ushort*)C1 : (ushort*)C2;
            #pragma unroll
            for (int m = 0; m < WM; ++m) {
                int grow0 = row0 + (wm * WM + m) * 16 + fg * 4;
                #pragma unroll
                for (int r = 0; r < 4; ++r)
                    dst[(size_t)(grow0 + r) * 256 + c] = f2bf(acc[m][n][r] + bv);
            }
        } else {
            float* dst = (float*)C0;
            #pragma unroll
            for (int m = 0; m < WM; ++m) {
                int grow0 = row0 + (wm * WM + m) * 16 + fg * 4;
                #pragma unroll
                for (int r = 0; r < 4; ++r)
                    dst[(size_t)(grow0 + r) * N + gcol] = acc[m][n][r] + bv;
            }
        }
    }
}

// ---------------------------------------------------------------------------
// Fused relational attention via async global_load_lds double-buffer.
// Grid 512 (exactly 2 blocks/CU), block = 8 items (same bt).
// Bias: 2 x 32KB f32 LDS slabs filled by gl_lds16 (fire-and-forget, zero
// VGPR) with pre-swizzled per-lane SOURCE addresses (T21); linear LDS dest.
// k, v register-resident; q double-buffered in regs (static idx via full
// unroll). A round has ZERO vmem waits except the end-of-round barrier's
// vmcnt(0), which drains the gll batch issued a full round earlier.
// Swizzle: f32x4 chunk c of row j holds source chunk c^(j&7); readers XOR.
// ---------------------------------------------------------------------------
__global__ __launch_bounds__(256, 2) void relattn_kernel(
    const ushort* __restrict__ qb, const ushort* __restrict__ kb,
    const ushort* __restrict__ vb, const float* __restrict__ bias,
    const int* __restrict__ mask, ushort* __restrict__ attn_out)
{
    __shared__ float slab[2][8192];        // 2 x 32KB f32 bias slabs

    const int b = blockIdx.x;              // 0..511
    const int item0 = b << 3;              // 8 items per block
    const int bt = b >> 2;                 // constant across the 8 items
    const int tid = threadIdx.x;
    const int w = tid >> 6, L = tid & 63;
    const int hw = L >> 5;
    const int h = 2 * w + hw;
    const int jd = L & 31;                 // j in scores, d in PV

    // ---- one-time register loads ----
    const bool alive = (mask[bt * 32 + jd] != 0);

    bf16x8 k8[4];
    const ushort* krow = kb + (size_t)(bt * 32 + jd) * 256 + h * 32;
    #pragma unroll
    for (int t = 0; t < 4; ++t) k8[t] = *(const bf16x8*)(krow + t * 8);

    ushort vreg[32];
    const ushort* vbase = vb + (size_t)bt * 8192 + tid;
    #pragma unroll
    for (int jj = 0; jj < 32; ++jj) vreg[jj] = vbase[(size_t)jj * 256];

    bf16x8 qreg[2][4];
    #pragma unroll
    for (int t = 0; t < 4; ++t)
        qreg[0][t] = *(const bf16x8*)(qb + (size_t)item0 * 256 + h * 32 + t * 8);

    const float* bbase = bias + (size_t)item0 * 8192;

    // gll stage: wave w fills rows {w, w+4, ..., w+28}; one row per instr.
    // dest base wave-uniform; per-lane source chunk = lane^(j&7).
    auto stage = [&](int item_idx, int buf) {
        const float* bi = bbase + (size_t)item_idx * 8192;
        #pragma unroll
        for (int g = 0; g < 8; ++g) {
            int j = g * 4 + w;
            gl_lds16(bi + j * 256 + ((L ^ (j & 7)) << 2), &slab[buf][j * 256]);
        }
    };

    stage(0, 0);
    __syncthreads();                       // prologue drain (once)

    #pragma unroll
    for (int it = 0; it < 8; ++it) {
        const float* cur = slab[it & 1];
        const int qcur = it & 1 ? 1 : 0;   // static after unroll

        // ---- issue next item's q (regs) then bias (gll) -> in flight all round ----
        if (it < 7) {
            #pragma unroll
            for (int t = 0; t < 4; ++t)
                qreg[(it + 1) & 1][t] = *(const bf16x8*)(
                    qb + (size_t)(item0 + it + 1) * 256 + h * 32 + t * 8);
            stage(it + 1, (it + 1) & 1);
        }

        // ---- scores: lane (h, jd); all operands in regs/LDS ----
        float s = 0.f;
        #pragma unroll
        for (int t = 0; t < 4; ++t) {
            bf16x8 q8 = qreg[qcur][t];
            int m0 = h * 8 + 2 * t;
            f32x4 b0 = *(const f32x4*)&cur[jd * 256 + ((m0 ^ (jd & 7)) << 2)];
            f32x4 b1 = *(const f32x4*)&cur[jd * 256 + (((m0 + 1) ^ (jd & 7)) << 2)];
            s += bf2f((ushort)q8[0]) * (bf2f((ushort)k8[t][0]) + b0[0])
               + bf2f((ushort)q8[1]) * (bf2f((ushort)k8[t][1]) + b0[1])
               + bf2f((ushort)q8[2]) * (bf2f((ushort)k8[t][2]) + b0[2])
               + bf2f((ushort)q8[3]) * (bf2f((ushort)k8[t][3]) + b0[3])
               + bf2f((ushort)q8[4]) * (bf2f((ushort)k8[t][4]) + b1[0])
               + bf2f((ushort)q8[5]) * (bf2f((ushort)k8[t][5]) + b1[1])
               + bf2f((ushort)q8[6]) * (bf2f((ushort)k8[t][6]) + b1[2])
               + bf2f((ushort)q8[7]) * (bf2f((ushort)k8[t][7]) + b1[3]);
        }
        s *= 0.17677669529663687f;         // 1/sqrt(32)
        s = alive ? s : -__builtin_inff();

        float m = s;
        #pragma unroll
        for (int off = 16; off; off >>= 1) m = fmaxf(m, __shfl_xor(m, off));
        const bool dead = (m == -__builtin_inff());
        float p = alive ? __expf(s - m) : 0.f;
        float l = p;
        #pragma unroll
        for (int off = 16; off; off >>= 1) l += __shfl_xor(l, off);
        float pn = dead ? 0.f : p / l;

        // ---- PV: col c = tid; v in regs, bias from LDS, p via shfl ----
        const int half32 = L & 32;
        const int cc = tid >> 2, clo = tid & 3;   // f32 chunk/elem of col
        float o0 = 0.f, o1 = 0.f, o2 = 0.f, o3 = 0.f;
        #pragma unroll
        for (int jq = 0; jq < 8; ++jq) {
            int j0 = jq * 4;
            float pa = __shfl(pn, half32 | (j0 + 0));
            float pb = __shfl(pn, half32 | (j0 + 1));
            float pc = __shfl(pn, half32 | (j0 + 2));
            float pd = __shfl(pn, half32 | (j0 + 3));
            float ba = cur[(j0 + 0) * 256 + ((((cc & 63) ^ ((j0 + 0) & 7)) << 2) | clo)];
            float bb = cur[(j0 + 1) * 256 + ((((cc & 63) ^ ((j0 + 1) & 7)) << 2) | clo)];
            float bc = cur[(j0 + 2) * 256 + ((((cc & 63) ^ ((j0 + 2) & 7)) << 2) | clo)];
            float bd = cur[(j0 + 3) * 256 + ((((cc & 63) ^ ((j0 + 3) & 7)) << 2) | clo)];
            o0 += pa * (bf2f(vreg[j0 + 0]) + ba);
            o1 += pb * (bf2f(vreg[j0 + 1]) + bb);
            o2 += pc * (bf2f(vreg[j0 + 2]) + bc);
            o3 += pd * (bf2f(vreg[j0 + 3]) + bd);
        }
        attn_out[(size_t)(item0 + it) * 256 + tid] = f2bf((o0 + o1) + (o2 + o3));

        // ---- end-of-round barrier: drains this round's gll+q; protects dbuf ----
        if (it < 7) __syncthreads();
    }
}

extern "C" void kernel_launch(void* const* d_in, const int* in_sizes, int n_in,
                              void* d_out, int out_size, void* d_ws, size_t ws_size,
                              hipStream_t stream) {
    const float* x      = (const float*)d_in[0];   // (4096,256)
    const float* bias_f = (const float*)d_in[1];   // (4096,32,256)
    const int*   mask   = (const int*)d_in[2];     // (4096,)
    const float* w_qkv  = (const float*)d_in[3];   // (256,768)
    const float* b_qkv  = (const float*)d_in[4];   // (768,)
    const float* w_proj = (const float*)d_in[5];   // (256,256)
    const float* b_proj = (const float*)d_in[6];   // (256,)
    float* out = (float*)d_out;                    // (4096,256)

    // workspace: q,k,v,attn_out each 4096*256 bf16 (2 MB) = 8.4 MB total
    ushort* qb = (ushort*)d_ws;
    ushort* kb = qb + (size_t)4096 * 256;
    ushort* vb = kb + (size_t)4096 * 256;
    ushort* ao = vb + (size_t)4096 * 256;

    // qkv = x @ w_qkv + b_qkv  ->  bf16 q/k/v   (M=4096, N=768, K=256)
    gemm_fused<64, 64, 2, 2, 0><<<dim3(12, 64), 256, 0, stream>>>(
        x, w_qkv, 768, b_qkv, qb, kb, vb, 256, 768);

    relattn_kernel<<<512, 256, 0, stream>>>(qb, kb, vb, bias_f, mask, ao);

    // out = attn_out @ w_proj + b_proj   (M=4096, N=256, K=256)
    gemm_fused<32, 64, 1, 4, 1><<<dim3(4, 128), 256, 0, stream>>>(
        ao, w_proj, 256, b_proj, out, nullptr, nullptr, 256, 256);
}